// Round 12
// baseline (245.246 us; speedup 1.0000x reference)
//
#include <hip/hip_runtime.h>
#include <math.h>

constexpr int Nn = 20000;
constexpr int Ee = 80000;
constexpr int Gg = 1000;

typedef _Float16 f16x8 __attribute__((ext_vector_type(8)));
typedef _Float16 f16x4 __attribute__((ext_vector_type(4)));
typedef _Float16 f16x2 __attribute__((ext_vector_type(2)));
typedef float    f32x4 __attribute__((ext_vector_type(4)));

__device__ __forceinline__ float eluf(float x){ return x > 0.f ? x : (expf(x) - 1.f); }

// ---- fused B permute for all 3 layers (ks-major fragment layout) ----
// bt[((ks*NF + n)*64 + l)*8 + j] = B[ks*32 + (l>>4)*8 + j][n*16 + (l&15)]
__device__ __forceinline__ void bt_emit(int idx, int lgNF, int MIR, int s, int MO,
                                        const float* __restrict__ w2,
                                        const float* __restrict__ b2,
                                        _Float16* __restrict__ bt){
  int NF = 1 << lgNF;
  int j  = idx & 7;
  int l  = (idx >> 3) & 63;
  int n  = (idx >> 9) & (NF - 1);
  int ks = idx >> (9 + lgNF);
  int col = n * 16 + (l & 15);
  int kk  = ks * 32 + ((l >> 4) << 3) + j;
  int k = kk >> s, i = kk & ((1 << s) - 1);
  float v = 0.f;
  if (i < MIR){
    if (k < 128)       v = w2[(size_t)k * (MIR * MO) + i * MO + col];
    else if (k == 128) v = b2[i * MO + col];
  }
  bt[idx] = (_Float16)v;
}

__global__ void bt_all(const float* __restrict__ w21, const float* __restrict__ b21,
                       const float* __restrict__ w22, const float* __restrict__ b22,
                       const float* __restrict__ w23, const float* __restrict__ b23,
                       _Float16* __restrict__ bt1, _Float16* __restrict__ bt2,
                       _Float16* __restrict__ bt3){
  int idx = blockIdx.x * 256 + threadIdx.x;
  if (idx < 36864)                 bt_emit(idx,                1, 5,  3, 32, w21, b21, bt1);
  else if (idx < 36864 + 270336)   bt_emit(idx - 36864,        2, 32, 5, 64, w22, b22, bt2);
  else if (idx < 839680)           bt_emit(idx - 307200,       2, 64, 6, 64, w23, b23, bt3);
}

// agg[n,o] = bias[o] + sum_i h[n,i]*root[i,o]   (h has row stride ldh)
template<int MI, int MO>
__global__ void node_kernel(const float* __restrict__ h, int ldh,
                            const float* __restrict__ root,
                            const float* __restrict__ bias, float* __restrict__ agg){
  int idx = blockIdx.x * blockDim.x + threadIdx.x;
  if (idx >= Nn * MO) return;
  int n = idx / MO, o = idx - n * MO;
  float s = bias[o];
  #pragma unroll
  for (int i = 0; i < MI; ++i) s += h[(size_t)n * ldh + i] * root[i * MO + o];
  agg[idx] = s;
}

// h_out = elu(agg_prev); agg_next = bias + h_out @ root
template<int MI, int MO>
__global__ __launch_bounds__(256) void elu_node_kernel(
    const float* __restrict__ agg_prev, const float* __restrict__ root,
    const float* __restrict__ bias, float* __restrict__ hout, float* __restrict__ agg_next){
  __shared__ float hl[32][MI + 1];
  int n0 = blockIdx.x * 32;
  int t  = threadIdx.x;
  for (int idx = t; idx < 32 * MI; idx += 256){
    int nl = idx / MI, i = idx - nl * MI;
    float v = eluf(agg_prev[(size_t)(n0 + nl) * MI + i]);
    hl[nl][i] = v;
    hout[(size_t)(n0 + nl) * MI + i] = v;
  }
  __syncthreads();
  for (int idx = t; idx < 32 * MO; idx += 256){
    int nl = idx / MO, o = idx - nl * MO;
    float s = bias[o];
    #pragma unroll 8
    for (int i = 0; i < MI; ++i) s += hl[nl][i] * root[i * MO + o];
    agg_next[(size_t)(n0 + nl) * MO + o] = s;
  }
}

// ---- MFMA edge kernel: 4 waves/WG = 4 K-quarters, 64 edges/WG ----
// B prologue issued at kernel top (hidden under hid compute); single barrier;
// depth-2 B ping-pong; hv pipelined one 4-U block ahead; phased LDS combine.
template<int MIR, int MIP, int MO, int HIDK, int LB>
__global__ __launch_bounds__(256, LB) void edge_mfma(
    const float* __restrict__ ea, const float* __restrict__ w1, const float* __restrict__ b1,
    const _Float16* __restrict__ bt, const float* __restrict__ h, int ldh,
    const int* __restrict__ src, const int* __restrict__ dst, float* __restrict__ agg)
{
  constexpr int NF   = MO / 16;
  constexpr int NBLK = MIP / 8;
  constexpr int KS   = (HIDK * MIP) / 32;          // 36 / 132 / 260
  constexpr int HIDP = (MIP == 8) ? 148 : ((MIP == 32) ? 140 : 136); // padded for prefetch
  constexpr int HID_B  = 64 * HIDP * 2;
  constexpr int HS_B   = 64 * MIP * 2;
  constexpr int COMB_B = 2 * 3 * NF * 64 * 16;     // phased overlay: 2 m x 3 s x n x lane x 16B
  constexpr int STG_B  = HID_B + HS_B;
  constexpr int POOL_B = (STG_B > COMB_B) ? STG_B : COMB_B;

  __shared__ __align__(16) char pool[POOL_B];
  _Float16* hidp = (_Float16*)pool;
  _Float16* hsp  = (_Float16*)(pool + HID_B);

  const int tid  = threadIdx.x;
  const int lane = tid & 63;
  const int wave = tid >> 6;           // K-quarter id
  const int c15  = lane & 15;
  const int g    = lane >> 4;
  const int e0   = blockIdx.x * 64;

  // K-quarter boundaries, rounded up to multiple of 4
  const int ksb = ((KS * wave / 4) + 3) & ~3;
  const int kse = (wave == 3) ? KS : ((KS * (wave + 1) / 4) + 3) & ~3;
  const int KSW = kse - ksb;

  // ---- B prologue issued FIRST: completes under the hid-compute phase ----
  const f16x8* __restrict__ btv = (const f16x8*)bt;
  f16x8 bqA[NF], bqB[NF];
  #pragma unroll
  for (int n = 0; n < NF; ++n){
    bqA[n] = btv[((size_t)(ksb + 0) * NF + n) * 64 + lane];
    bqB[n] = btv[((size_t)(ksb + 1) * NF + n) * 64 + lane];
  }

  // phase 1: hid rows [0, HIDK) = relu(ea@w1+b1); row 128 = 1 (bias), rows >128 = 0
  // (ea read direct from global: 1.3 KB/WG, L1-broadcast across threads sharing e)
  for (int t = tid; t < 64 * HIDK; t += 256){
    int e = t / HIDK, k = t - e * HIDK;
    float s;
    if (k < 128){
      s = b1[k];
      #pragma unroll
      for (int j = 0; j < 5; ++j) s += ea[(size_t)(e0 + e) * 5 + j] * w1[j * 128 + k];
      s = fmaxf(s, 0.f);
    } else s = (k == 128) ? 1.f : 0.f;
    hidp[e * HIDP + k] = (_Float16)s;
  }
  // gather h_src (float4 vectorized, f16, zero-pad i>=MIR), block-swizzled
  constexpr int IV = MIP / 4;
  for (int t = tid; t < 64 * IV; t += 256){
    int e = t / IV, i4 = (t - e * IV) * 4;
    int se = src[e0 + e];
    f32x4 hv4 = *(const f32x4*)&h[(size_t)se * ldh + i4];
    _Float16 o4[4];
    #pragma unroll
    for (int q = 0; q < 4; ++q) o4[q] = (i4 + q < MIR) ? (_Float16)hv4[q] : (_Float16)0.f;
    int bw = ((i4 >> 3) ^ (e & (NBLK - 1)));
    *(f16x4*)&hsp[e * MIP + ((bw << 3) | (i4 & 7))] = *(const f16x4*)o4;
  }
  __syncthreads();

  int er_[4];
  #pragma unroll
  for (int m = 0; m < 4; ++m) er_[m] = m * 16 + c15;

  f32x4 acc[4][NF];
  #pragma unroll
  for (int m = 0; m < 4; ++m)
    #pragma unroll
    for (int n = 0; n < NF; ++n) acc[m][n] = (f32x4){0.f, 0.f, 0.f, 0.f};

  // A hoist
  f16x8 hsh[4][2];
  #pragma unroll
  for (int m = 0; m < 4; ++m){
    const int er = er_[m];
    if constexpr (MIP == 8){
      hsh[m][0] = *(const f16x8*)&hsp[er * MIP];
      hsh[m][1] = hsh[m][0];
    } else if constexpr (MIP == 32){
      int blk = g ^ (er & 3);
      hsh[m][0] = *(const f16x8*)&hsp[er * MIP + (blk << 3)];
      hsh[m][1] = hsh[m][0];
    } else {
      int b0 = g ^ (er & 7), b1x = (4 + g) ^ (er & 7);
      hsh[m][0] = *(const f16x8*)&hsp[er * MIP + (b0 << 3)];
      hsh[m][1] = *(const f16x8*)&hsp[er * MIP + (b1x << 3)];
    }
  }

#define EDGE_SUB(U, BQ)                                                         \
  {                                                                             \
    _Pragma("unroll")                                                           \
    for (int m = 0; m < 4; ++m){                                                \
      _Float16 hv;                                                              \
      f16x8 hs8;                                                                \
      if constexpr (MIP == 64){ hv = hvC2[m][(U) >> 1]; hs8 = hsh[m][(U) & 1]; }\
      else if constexpr (MIP == 32){ hv = hvC4[m][(U)]; hs8 = hsh[m][0]; }      \
      else { hv = hidp[er_[m] * HIDP + ((ksb + u + (U)) << 2) + g];             \
             hs8 = hsh[m][0]; }                                                 \
      f16x8 hvv = {hv, hv, hv, hv, hv, hv, hv, hv};                             \
      f16x8 av  = hs8 * hvv;                                                    \
      _Pragma("unroll")                                                         \
      for (int n = 0; n < NF; ++n)                                              \
        acc[m][n] = __builtin_amdgcn_mfma_f32_16x16x32_f16(av, BQ[n],           \
                                                           acc[m][n], 0, 0, 0);\
    }                                                                           \
    _Pragma("unroll")                                                           \
    for (int n = 0; n < NF; ++n)                                                \
      BQ[n] = btv[((size_t)(ksb + u + (U) + 2) * NF + n) * 64 + lane];          \
  }

  // hv pipeline registers (only the MIP-matching set is used)
  f16x2 hvC2[4], hvN2[4];
  f16x4 hvC4[4], hvN4[4];
  if constexpr (MIP == 64){
    #pragma unroll
    for (int m = 0; m < 4; ++m)
      hvC2[m] = *(const f16x2*)&hidp[er_[m] * HIDP + (ksb >> 1)];
  } else if constexpr (MIP == 32){
    #pragma unroll
    for (int m = 0; m < 4; ++m)
      hvC4[m] = *(const f16x4*)&hidp[er_[m] * HIDP + ksb];
  }

  for (int u = 0; u < KSW; u += 4){
    if constexpr (MIP == 64){
      #pragma unroll
      for (int m = 0; m < 4; ++m)
        hvN2[m] = *(const f16x2*)&hidp[er_[m] * HIDP + ((ksb + u + 4) >> 1)];
    } else if constexpr (MIP == 32){
      #pragma unroll
      for (int m = 0; m < 4; ++m)
        hvN4[m] = *(const f16x4*)&hidp[er_[m] * HIDP + (ksb + u + 4)];
    }
    __builtin_amdgcn_s_setprio(1);
    EDGE_SUB(0, bqA)
    EDGE_SUB(1, bqB)
    EDGE_SUB(2, bqA)
    EDGE_SUB(3, bqB)
    __builtin_amdgcn_s_setprio(0);
    #pragma unroll
    for (int m = 0; m < 4; ++m){ hvC2[m] = hvN2[m]; hvC4[m] = hvN4[m]; }
  }
#undef EDGE_SUB

  // ---- phased combine: round A (m=0,1), round B (m=2,3), then parallel atomics ----
  __syncthreads();
  float* comb = (float*)pool;
  #pragma unroll
  for (int m = 0; m < 2; ++m) if (m != wave){
    int s = wave - (wave > m ? 1 : 0);
    #pragma unroll
    for (int n = 0; n < NF; ++n)
      *(f32x4*)&comb[(((m * 3 + s) * NF + n) * 64 + lane) * 4] = acc[m][n];
  }
  __syncthreads();
  #pragma unroll
  for (int m = 0; m < 2; ++m) if (m == wave){
    #pragma unroll
    for (int n = 0; n < NF; ++n)
      #pragma unroll
      for (int s = 0; s < 3; ++s)
        acc[m][n] += *(const f32x4*)&comb[(((m * 3 + s) * NF + n) * 64 + lane) * 4];
  }
  __syncthreads();
  #pragma unroll
  for (int m = 2; m < 4; ++m) if (m != wave){
    int s = wave - (wave > m ? 1 : 0);
    #pragma unroll
    for (int n = 0; n < NF; ++n)
      *(f32x4*)&comb[((((m - 2) * 3 + s) * NF + n) * 64 + lane) * 4] = acc[m][n];
  }
  __syncthreads();
  #pragma unroll
  for (int m = 2; m < 4; ++m) if (m == wave){
    #pragma unroll
    for (int n = 0; n < NF; ++n)
      #pragma unroll
      for (int s = 0; s < 3; ++s)
        acc[m][n] += *(const f32x4*)&comb[((((m - 2) * 3 + s) * NF + n) * 64 + lane) * 4];
  }
  // all waves atomic their own m-fragment in parallel (dst read direct)
  #pragma unroll
  for (int m = 0; m < 4; ++m) if (m == wave){
    int d_[4];
    #pragma unroll
    for (int j = 0; j < 4; ++j) d_[j] = dst[e0 + m * 16 + (g << 2) + j];
    #pragma unroll
    for (int n = 0; n < NF; ++n)
      #pragma unroll
      for (int j = 0; j < 4; ++j)
        atomicAdd(&agg[(size_t)d_[j] * MO + n * 16 + c15], acc[m][n][j]);
  }
}

// ---- fused mean-pool + head MLP: one 64-thread WG per graph (batch is sorted) ----
__global__ __launch_bounds__(64) void pool_head_kernel(
    const float* __restrict__ agg3, const float* __restrict__ x,
    const int* __restrict__ batch,
    const float* __restrict__ fc1w, const float* __restrict__ fc1b,
    const float* __restrict__ fc2w, const float* __restrict__ fc2b,
    const float* __restrict__ fc3w, const float* __restrict__ fc3b,
    float* __restrict__ out)
{
  int gph  = blockIdx.x;
  int lane = threadIdx.x;
  int lo = 0, hi = Nn;
  while (lo < hi){ int mid = (lo + hi) >> 1; if (batch[mid] < gph) lo = mid + 1; else hi = mid; }
  int start = lo;
  hi = Nn;
  while (lo < hi){ int mid = (lo + hi) >> 1; if (batch[mid] < gph + 1) lo = mid + 1; else hi = mid; }
  int end = lo;

  float s0 = 0.f, s1 = 0.f;
  for (int n = start; n < end; ++n){
    s0 += eluf(agg3[(size_t)n * 64 + lane]);
    if (lane < 11) s1 += x[(size_t)n * 16 + 5 + lane];
  }
  float inv = 1.f / fmaxf((float)(end - start), 1.f);

  __shared__ float m[75];
  __shared__ float a1[32];
  __shared__ float a2[16];
  m[lane] = s0 * inv;
  if (lane < 11) m[64 + lane] = s1 * inv;
  __syncthreads();
  if (lane < 32){
    float s = fc1b[lane];
    for (int f = 0; f < 75; ++f) s += m[f] * fc1w[f * 32 + lane];
    a1[lane] = eluf(s);
  }
  __syncthreads();
  if (lane < 16){
    float s = fc2b[lane];
    #pragma unroll
    for (int i = 0; i < 32; ++i) s += a1[i] * fc2w[i * 16 + lane];
    a2[lane] = eluf(s);
  }
  __syncthreads();
  if (lane == 0){
    float s = fc3b[0];
    #pragma unroll
    for (int i = 0; i < 16; ++i) s += a2[i] * fc3w[i];
    out[gph] = s;
  }
}

extern "C" void kernel_launch(void* const* d_in, const int* in_sizes, int n_in,
                              void* d_out, int out_size, void* d_ws, size_t ws_size,
                              hipStream_t stream)
{
  (void)in_sizes; (void)n_in; (void)out_size; (void)ws_size;
  const float* x     = (const float*)d_in[0];
  const int*   ei    = (const int*)d_in[1];
  const float* ea    = (const float*)d_in[2];
  const int*   batch = (const int*)d_in[3];
  const float* cw1[3]   = {(const float*)d_in[4],  (const float*)d_in[10], (const float*)d_in[16]};
  const float* cb1[3]   = {(const float*)d_in[5],  (const float*)d_in[11], (const float*)d_in[17]};
  const float* cw2[3]   = {(const float*)d_in[6],  (const float*)d_in[12], (const float*)d_in[18]};
  const float* cb2[3]   = {(const float*)d_in[7],  (const float*)d_in[13], (const float*)d_in[19]};
  const float* croot[3] = {(const float*)d_in[8],  (const float*)d_in[14], (const float*)d_in[20]};
  const float* cbias[3] = {(const float*)d_in[9],  (const float*)d_in[15], (const float*)d_in[21]};
  const float* fc1w = (const float*)d_in[22];
  const float* fc1b = (const float*)d_in[23];
  const float* fc2w = (const float*)d_in[24];
  const float* fc2b = (const float*)d_in[25];
  const float* fc3w = (const float*)d_in[26];
  const float* fc3b = (const float*)d_in[27];
  float* out = (float*)d_out;

  float* ws   = (float*)d_ws;
  float* h    = ws;                              // N*64
  float* aggA = h + (size_t)Nn * 64;             // N*64
  float* aggB = aggA + (size_t)Nn * 64;          // N*64
  _Float16* bt1 = (_Float16*)(aggB + (size_t)Nn * 64);  // 2*(36+4)*512  = 40960
  _Float16* bt2 = bt1 + 40960;                   // 4*(132+4)*512 = 278528
  _Float16* bt3 = bt2 + 278528;                  // 4*(260+4)*512 = 540672

  const int* src = ei;
  const int* dst = ei + Ee;

  bt_all<<<3280, 256, 0, stream>>>(cw2[0], cb2[0], cw2[1], cb2[1], cw2[2], cb2[2], bt1, bt2, bt3);

  // ---- layer 1: MI=5 (pad 8), MO=32; h = x (stride 16) ----
  node_kernel<5, 32><<<(Nn * 32 + 255) / 256, 256, 0, stream>>>(x, 16, croot[0], cbias[0], aggA);
  edge_mfma<5, 8, 32, 144, 4><<<Ee / 64, 256, 0, stream>>>(ea, cw1[0], cb1[0], bt1, x, 16, src, dst, aggA);

  // ---- layer 2: MI=32, MO=64 ----
  elu_node_kernel<32, 64><<<(Nn + 31) / 32, 256, 0, stream>>>(aggA, croot[1], cbias[1], h, aggB);
  edge_mfma<32, 32, 64, 132, 3><<<Ee / 64, 256, 0, stream>>>(ea, cw1[1], cb1[1], bt2, h, 32, src, dst, aggB);

  // ---- layer 3: MI=64, MO=64 ----
  elu_node_kernel<64, 64><<<(Nn + 31) / 32, 256, 0, stream>>>(aggB, croot[2], cbias[2], h, aggA);
  edge_mfma<64, 64, 64, 130, 3><<<Ee / 64, 256, 0, stream>>>(ea, cw1[2], cb1[2], bt3, h, 64, src, dst, aggA);

  // ---- fused mean-pool + head ----
  pool_head_kernel<<<Gg, 64, 0, stream>>>(aggA, x, batch, fc1w, fc1b, fc2w, fc2b, fc3w, fc3b, out);
}

// Round 13
// 217.792 us; speedup vs baseline: 1.1261x; 1.1261x over previous
//
#include <hip/hip_runtime.h>
#include <math.h>

constexpr int Nn = 20000;
constexpr int Ee = 80000;
constexpr int Gg = 1000;

typedef _Float16 f16x8 __attribute__((ext_vector_type(8)));
typedef _Float16 f16x4 __attribute__((ext_vector_type(4)));
typedef _Float16 f16x2 __attribute__((ext_vector_type(2)));
typedef float    f32x4 __attribute__((ext_vector_type(4)));

__device__ __forceinline__ float eluf(float x){ return x > 0.f ? x : (expf(x) - 1.f); }

// ---- fused B permute for all 3 layers (ks-major fragment layout) ----
// bt[((ks*NF + n)*64 + l)*8 + j] = B[ks*32 + (l>>4)*8 + j][n*16 + (l&15)]
__device__ __forceinline__ void bt_emit(int idx, int lgNF, int MIR, int s, int MO,
                                        const float* __restrict__ w2,
                                        const float* __restrict__ b2,
                                        _Float16* __restrict__ bt){
  int NF = 1 << lgNF;
  int j  = idx & 7;
  int l  = (idx >> 3) & 63;
  int n  = (idx >> 9) & (NF - 1);
  int ks = idx >> (9 + lgNF);
  int col = n * 16 + (l & 15);
  int kk  = ks * 32 + ((l >> 4) << 3) + j;
  int k = kk >> s, i = kk & ((1 << s) - 1);
  float v = 0.f;
  if (i < MIR){
    if (k < 128)       v = w2[(size_t)k * (MIR * MO) + i * MO + col];
    else if (k == 128) v = b2[i * MO + col];
  }
  bt[idx] = (_Float16)v;
}

// bt permutes for all layers + layer-1 node term (aggA = bias1 + x[:, :5] @ root1)
__global__ void bt_node_all(const float* __restrict__ w21, const float* __restrict__ b21,
                            const float* __restrict__ w22, const float* __restrict__ b22,
                            const float* __restrict__ w23, const float* __restrict__ b23,
                            _Float16* __restrict__ bt1, _Float16* __restrict__ bt2,
                            _Float16* __restrict__ bt3,
                            const float* __restrict__ x, const float* __restrict__ root1,
                            const float* __restrict__ bias1, float* __restrict__ aggA){
  int idx = blockIdx.x * 256 + threadIdx.x;
  if (idx < 36864)                 bt_emit(idx,          1, 5,  3, 32, w21, b21, bt1);
  else if (idx < 36864 + 270336)   bt_emit(idx - 36864,  2, 32, 5, 64, w22, b22, bt2);
  else if (idx < 839680)           bt_emit(idx - 307200, 2, 64, 6, 64, w23, b23, bt3);
  else {
    int t = idx - 839680;
    if (t < Nn * 32){
      int n = t >> 5, o = t & 31;
      float s = bias1[o];
      #pragma unroll
      for (int i = 0; i < 5; ++i) s += x[(size_t)n * 16 + i] * root1[i * 32 + o];
      aggA[t] = s;
    }
  }
}

// h_out = elu(agg_prev); agg_next = bias + h_out @ root
template<int MI, int MO>
__global__ __launch_bounds__(256) void elu_node_kernel(
    const float* __restrict__ agg_prev, const float* __restrict__ root,
    const float* __restrict__ bias, float* __restrict__ hout, float* __restrict__ agg_next){
  __shared__ float hl[32][MI + 1];
  int n0 = blockIdx.x * 32;
  int t  = threadIdx.x;
  for (int idx = t; idx < 32 * MI; idx += 256){
    int nl = idx / MI, i = idx - nl * MI;
    float v = eluf(agg_prev[(size_t)(n0 + nl) * MI + i]);
    hl[nl][i] = v;
    hout[(size_t)(n0 + nl) * MI + i] = v;
  }
  __syncthreads();
  for (int idx = t; idx < 32 * MO; idx += 256){
    int nl = idx / MO, o = idx - nl * MO;
    float s = bias[o];
    #pragma unroll 8
    for (int i = 0; i < MI; ++i) s += hl[nl][i] * root[i * MO + o];
    agg_next[(size_t)(n0 + nl) * MO + o] = s;
  }
}

// ---- MFMA edge kernel: 4 waves/WG = 4 K-quarters, 64 edges/WG ----
// (round-10 measured-best config: depth-2 B ping-pong, hv pipelined one 4-U
//  block ahead, setprio around MFMA cluster, phased LDS combine)
template<int MIR, int MIP, int MO, int HIDK, int LB>
__global__ __launch_bounds__(256, LB) void edge_mfma(
    const float* __restrict__ ea, const float* __restrict__ w1, const float* __restrict__ b1,
    const _Float16* __restrict__ bt, const float* __restrict__ h, int ldh,
    const int* __restrict__ src, const int* __restrict__ dst, float* __restrict__ agg)
{
  constexpr int NF   = MO / 16;
  constexpr int NBLK = MIP / 8;
  constexpr int KS   = (HIDK * MIP) / 32;          // 36 / 132 / 260
  constexpr int HIDP = (MIP == 8) ? 148 : ((MIP == 32) ? 140 : 136); // padded for prefetch
  constexpr int HID_B  = 64 * HIDP * 2;
  constexpr int HS_B   = 64 * MIP * 2;
  constexpr int COMB_B = 2 * 3 * NF * 64 * 16;     // phased overlay: 2 m x 3 s x n x lane x 16B
  constexpr int EA_O   = HID_B + HS_B;
  constexpr int SRC_O  = EA_O + 1280;
  constexpr int STG_E  = SRC_O + 256;
  constexpr int DST_O  = (STG_E > COMB_B) ? STG_E : COMB_B;

  __shared__ __align__(16) char pool[DST_O + 256];
  _Float16* hidp = (_Float16*)pool;
  _Float16* hsp  = (_Float16*)(pool + HID_B);
  float*    eap  = (float*)(pool + EA_O);
  int*      src_l = (int*)(pool + SRC_O);
  int*      dst_l = (int*)(pool + DST_O);

  const int tid  = threadIdx.x;
  const int lane = tid & 63;
  const int wave = tid >> 6;           // K-quarter id
  const int c15  = lane & 15;
  const int g    = lane >> 4;
  const int e0   = blockIdx.x * 64;

  // K-quarter boundaries, rounded up to multiple of 4
  const int ksb = ((KS * wave / 4) + 3) & ~3;
  const int kse = (wave == 3) ? KS : ((KS * (wave + 1) / 4) + 3) & ~3;
  const int KSW = kse - ksb;

  // phase 0: stage tile data
  for (int t = tid; t < 320; t += 256) eap[t] = ea[(size_t)e0 * 5 + t];
  if (tid < 64){ src_l[tid] = src[e0 + tid]; dst_l[tid] = dst[e0 + tid]; }
  __syncthreads();

  // phase 1: hid rows [0, HIDK) = relu(ea@w1+b1); row 128 = 1 (bias), rows >128 = 0
  for (int t = tid; t < 64 * HIDK; t += 256){
    int e = t / HIDK, k = t - e * HIDK;
    float s;
    if (k < 128){
      s = b1[k];
      #pragma unroll
      for (int j = 0; j < 5; ++j) s += eap[e * 5 + j] * w1[j * 128 + k];
      s = fmaxf(s, 0.f);
    } else s = (k == 128) ? 1.f : 0.f;
    hidp[e * HIDP + k] = (_Float16)s;
  }
  // gather h_src (float4 vectorized, f16, zero-pad i>=MIR), block-swizzled
  constexpr int IV = MIP / 4;
  for (int t = tid; t < 64 * IV; t += 256){
    int e = t / IV, i4 = (t - e * IV) * 4;
    f32x4 hv4 = *(const f32x4*)&h[(size_t)src_l[e] * ldh + i4];
    _Float16 o4[4];
    #pragma unroll
    for (int q = 0; q < 4; ++q) o4[q] = (i4 + q < MIR) ? (_Float16)hv4[q] : (_Float16)0.f;
    int bw = ((i4 >> 3) ^ (e & (NBLK - 1)));
    *(f16x4*)&hsp[e * MIP + ((bw << 3) | (i4 & 7))] = *(const f16x4*)o4;
  }
  __syncthreads();

  const f16x8* __restrict__ btv = (const f16x8*)bt;
  int er_[4];
  #pragma unroll
  for (int m = 0; m < 4; ++m) er_[m] = m * 16 + c15;

  f32x4 acc[4][NF];
  #pragma unroll
  for (int m = 0; m < 4; ++m)
    #pragma unroll
    for (int n = 0; n < NF; ++n) acc[m][n] = (f32x4){0.f, 0.f, 0.f, 0.f};

  // A hoist
  f16x8 hsh[4][2];
  #pragma unroll
  for (int m = 0; m < 4; ++m){
    const int er = er_[m];
    if constexpr (MIP == 8){
      hsh[m][0] = *(const f16x8*)&hsp[er * MIP];
      hsh[m][1] = hsh[m][0];
    } else if constexpr (MIP == 32){
      int blk = g ^ (er & 3);
      hsh[m][0] = *(const f16x8*)&hsp[er * MIP + (blk << 3)];
      hsh[m][1] = hsh[m][0];
    } else {
      int b0 = g ^ (er & 7), b1x = (4 + g) ^ (er & 7);
      hsh[m][0] = *(const f16x8*)&hsp[er * MIP + (b0 << 3)];
      hsh[m][1] = *(const f16x8*)&hsp[er * MIP + (b1x << 3)];
    }
  }

  // B prologue: depth-2 ping-pong
  f16x8 bqA[NF], bqB[NF];
  #pragma unroll
  for (int n = 0; n < NF; ++n){
    bqA[n] = btv[((size_t)(ksb + 0) * NF + n) * 64 + lane];
    bqB[n] = btv[((size_t)(ksb + 1) * NF + n) * 64 + lane];
  }

#define EDGE_SUB(U, BQ)                                                         \
  {                                                                             \
    _Pragma("unroll")                                                           \
    for (int m = 0; m < 4; ++m){                                                \
      _Float16 hv;                                                              \
      f16x8 hs8;                                                                \
      if constexpr (MIP == 64){ hv = hvC2[m][(U) >> 1]; hs8 = hsh[m][(U) & 1]; }\
      else if constexpr (MIP == 32){ hv = hvC4[m][(U)]; hs8 = hsh[m][0]; }      \
      else { hv = hidp[er_[m] * HIDP + ((ksb + u + (U)) << 2) + g];             \
             hs8 = hsh[m][0]; }                                                 \
      f16x8 hvv = {hv, hv, hv, hv, hv, hv, hv, hv};                             \
      f16x8 av  = hs8 * hvv;                                                    \
      _Pragma("unroll")                                                         \
      for (int n = 0; n < NF; ++n)                                              \
        acc[m][n] = __builtin_amdgcn_mfma_f32_16x16x32_f16(av, BQ[n],           \
                                                           acc[m][n], 0, 0, 0);\
    }                                                                           \
    _Pragma("unroll")                                                           \
    for (int n = 0; n < NF; ++n)                                                \
      BQ[n] = btv[((size_t)(ksb + u + (U) + 2) * NF + n) * 64 + lane];          \
  }

  // hv pipeline registers (only the MIP-matching set is used)
  f16x2 hvC2[4], hvN2[4];
  f16x4 hvC4[4], hvN4[4];
  if constexpr (MIP == 64){
    #pragma unroll
    for (int m = 0; m < 4; ++m)
      hvC2[m] = *(const f16x2*)&hidp[er_[m] * HIDP + (ksb >> 1)];
  } else if constexpr (MIP == 32){
    #pragma unroll
    for (int m = 0; m < 4; ++m)
      hvC4[m] = *(const f16x4*)&hidp[er_[m] * HIDP + ksb];
  }

  for (int u = 0; u < KSW; u += 4){
    if constexpr (MIP == 64){
      #pragma unroll
      for (int m = 0; m < 4; ++m)
        hvN2[m] = *(const f16x2*)&hidp[er_[m] * HIDP + ((ksb + u + 4) >> 1)];
    } else if constexpr (MIP == 32){
      #pragma unroll
      for (int m = 0; m < 4; ++m)
        hvN4[m] = *(const f16x4*)&hidp[er_[m] * HIDP + (ksb + u + 4)];
    }
    __builtin_amdgcn_s_setprio(1);
    EDGE_SUB(0, bqA)
    EDGE_SUB(1, bqB)
    EDGE_SUB(2, bqA)
    EDGE_SUB(3, bqB)
    __builtin_amdgcn_s_setprio(0);
    #pragma unroll
    for (int m = 0; m < 4; ++m){ hvC2[m] = hvN2[m]; hvC4[m] = hvN4[m]; }
  }
#undef EDGE_SUB

  // ---- phased combine: round A (m=0,1), round B (m=2,3), then parallel atomics ----
  __syncthreads();
  float* comb = (float*)pool;
  #pragma unroll
  for (int m = 0; m < 2; ++m) if (m != wave){
    int s = wave - (wave > m ? 1 : 0);
    #pragma unroll
    for (int n = 0; n < NF; ++n)
      *(f32x4*)&comb[(((m * 3 + s) * NF + n) * 64 + lane) * 4] = acc[m][n];
  }
  __syncthreads();
  #pragma unroll
  for (int m = 0; m < 2; ++m) if (m == wave){
    #pragma unroll
    for (int n = 0; n < NF; ++n)
      #pragma unroll
      for (int s = 0; s < 3; ++s)
        acc[m][n] += *(const f32x4*)&comb[(((m * 3 + s) * NF + n) * 64 + lane) * 4];
  }
  __syncthreads();
  #pragma unroll
  for (int m = 2; m < 4; ++m) if (m != wave){
    int s = wave - (wave > m ? 1 : 0);
    #pragma unroll
    for (int n = 0; n < NF; ++n)
      *(f32x4*)&comb[((((m - 2) * 3 + s) * NF + n) * 64 + lane) * 4] = acc[m][n];
  }
  __syncthreads();
  #pragma unroll
  for (int m = 2; m < 4; ++m) if (m == wave){
    #pragma unroll
    for (int n = 0; n < NF; ++n)
      #pragma unroll
      for (int s = 0; s < 3; ++s)
        acc[m][n] += *(const f32x4*)&comb[((((m - 2) * 3 + s) * NF + n) * 64 + lane) * 4];
  }
  // all waves atomic their own m-fragment in parallel
  #pragma unroll
  for (int m = 0; m < 4; ++m) if (m == wave){
    #pragma unroll
    for (int n = 0; n < NF; ++n)
      #pragma unroll
      for (int j = 0; j < 4; ++j){
        int er = m * 16 + (g << 2) + j;
        atomicAdd(&agg[(size_t)dst_l[er] * MO + n * 16 + c15], acc[m][n][j]);
      }
  }
}

// ---- fused mean-pool + head MLP: one 64-thread WG per graph (batch is sorted) ----
__global__ __launch_bounds__(64) void pool_head_kernel(
    const float* __restrict__ agg3, const float* __restrict__ x,
    const int* __restrict__ batch,
    const float* __restrict__ fc1w, const float* __restrict__ fc1b,
    const float* __restrict__ fc2w, const float* __restrict__ fc2b,
    const float* __restrict__ fc3w, const float* __restrict__ fc3b,
    float* __restrict__ out)
{
  int gph  = blockIdx.x;
  int lane = threadIdx.x;
  int lo = 0, hi = Nn;
  while (lo < hi){ int mid = (lo + hi) >> 1; if (batch[mid] < gph) lo = mid + 1; else hi = mid; }
  int start = lo;
  hi = Nn;
  while (lo < hi){ int mid = (lo + hi) >> 1; if (batch[mid] < gph + 1) lo = mid + 1; else hi = mid; }
  int end = lo;

  float s0 = 0.f, s1 = 0.f;
  for (int n = start; n < end; ++n){
    s0 += eluf(agg3[(size_t)n * 64 + lane]);
    if (lane < 11) s1 += x[(size_t)n * 16 + 5 + lane];
  }
  float inv = 1.f / fmaxf((float)(end - start), 1.f);

  __shared__ float m[75];
  __shared__ float a1[32];
  __shared__ float a2[16];
  m[lane] = s0 * inv;
  if (lane < 11) m[64 + lane] = s1 * inv;
  __syncthreads();
  if (lane < 32){
    float s = fc1b[lane];
    for (int f = 0; f < 75; ++f) s += m[f] * fc1w[f * 32 + lane];
    a1[lane] = eluf(s);
  }
  __syncthreads();
  if (lane < 16){
    float s = fc2b[lane];
    #pragma unroll
    for (int i = 0; i < 32; ++i) s += a1[i] * fc2w[i * 16 + lane];
    a2[lane] = eluf(s);
  }
  __syncthreads();
  if (lane == 0){
    float s = fc3b[0];
    #pragma unroll
    for (int i = 0; i < 16; ++i) s += a2[i] * fc3w[i];
    out[gph] = s;
  }
}

extern "C" void kernel_launch(void* const* d_in, const int* in_sizes, int n_in,
                              void* d_out, int out_size, void* d_ws, size_t ws_size,
                              hipStream_t stream)
{
  (void)in_sizes; (void)n_in; (void)out_size; (void)ws_size;
  const float* x     = (const float*)d_in[0];
  const int*   ei    = (const int*)d_in[1];
  const float* ea    = (const float*)d_in[2];
  const int*   batch = (const int*)d_in[3];
  const float* cw1[3]   = {(const float*)d_in[4],  (const float*)d_in[10], (const float*)d_in[16]};
  const float* cb1[3]   = {(const float*)d_in[5],  (const float*)d_in[11], (const float*)d_in[17]};
  const float* cw2[3]   = {(const float*)d_in[6],  (const float*)d_in[12], (const float*)d_in[18]};
  const float* cb2[3]   = {(const float*)d_in[7],  (const float*)d_in[13], (const float*)d_in[19]};
  const float* croot[3] = {(const float*)d_in[8],  (const float*)d_in[14], (const float*)d_in[20]};
  const float* cbias[3] = {(const float*)d_in[9],  (const float*)d_in[15], (const float*)d_in[21]};
  const float* fc1w = (const float*)d_in[22];
  const float* fc1b = (const float*)d_in[23];
  const float* fc2w = (const float*)d_in[24];
  const float* fc2b = (const float*)d_in[25];
  const float* fc3w = (const float*)d_in[26];
  const float* fc3b = (const float*)d_in[27];
  float* out = (float*)d_out;

  float* ws   = (float*)d_ws;
  float* h    = ws;                              // N*64
  float* aggA = h + (size_t)Nn * 64;             // N*64
  float* aggB = aggA + (size_t)Nn * 64;          // N*64
  _Float16* bt1 = (_Float16*)(aggB + (size_t)Nn * 64);  // 2*(36+4)*512  = 40960
  _Float16* bt2 = bt1 + 40960;                   // 4*(132+4)*512 = 278528
  _Float16* bt3 = bt2 + 278528;                  // 4*(260+4)*512 = 540672

  const int* src = ei;
  const int* dst = ei + Ee;

  // bt permutes + layer-1 node term, fused (one launch)
  bt_node_all<<<(839680 + Nn * 32 + 255) / 256, 256, 0, stream>>>(
      cw2[0], cb2[0], cw2[1], cb2[1], cw2[2], cb2[2], bt1, bt2, bt3,
      x, croot[0], cbias[0], aggA);

  // ---- layer 1: MI=5 (pad 8), MO=32; h = x (stride 16) ----
  edge_mfma<5, 8, 32, 144, 4><<<Ee / 64, 256, 0, stream>>>(ea, cw1[0], cb1[0], bt1, x, 16, src, dst, aggA);

  // ---- layer 2: MI=32, MO=64 ----
  elu_node_kernel<32, 64><<<(Nn + 31) / 32, 256, 0, stream>>>(aggA, croot[1], cbias[1], h, aggB);
  edge_mfma<32, 32, 64, 132, 3><<<Ee / 64, 256, 0, stream>>>(ea, cw1[1], cb1[1], bt2, h, 32, src, dst, aggB);

  // ---- layer 3: MI=64, MO=64 ----
  elu_node_kernel<64, 64><<<(Nn + 31) / 32, 256, 0, stream>>>(aggB, croot[2], cbias[2], h, aggA);
  edge_mfma<64, 64, 64, 130, 3><<<Ee / 64, 256, 0, stream>>>(ea, cw1[2], cb1[2], bt3, h, 64, src, dst, aggA);

  // ---- fused mean-pool + head ----
  pool_head_kernel<<<Gg, 64, 0, stream>>>(aggA, x, batch, fc1w, fc1b, fc2w, fc2b, fc3w, fc3b, out);
}